// Round 8
// baseline (266.691 us; speedup 1.0000x reference)
//
#include <hip/hip_runtime.h>

#define D 32
#define GN 64            // receiver nodes per bin
#define CAPB_MAX 1600    // entries per bin (avg 1280, +8.9 sigma)
#define CHUNK_A 8192     // edges per bucket block
#define THREADS_A 512
#define THREADS_G 512

// K-1: zero cursor + ovfcnt (~6 KB). Replaces hipMemsetAsync whose
// fillBufferAligned kernel ran at 176 GB/s for 147 us (R7 top dispatch).
__global__ void zero_small(int* __restrict__ p, int n) {
    const int i = blockIdx.x * 256 + threadIdx.x;
    if (i < n) p[i] = 0;
}

// K0: P_src = W_aggr @ W_eu @ W_src, similarly edge, rx. One block (32,32).
__global__ void combine_weights(const float* __restrict__ W_src,
                                const float* __restrict__ W_edge,
                                const float* __restrict__ W_rx,
                                const float* __restrict__ W_eu,
                                const float* __restrict__ W_aggr,
                                float* __restrict__ P_out) {
    __shared__ float sWa[D][D], sWe[D][D], sP2[D][D + 1];
    __shared__ float sW1[D][D], sW2[D][D], sW3[D][D];
    const int j = threadIdx.x, i = threadIdx.y;
    sWa[i][j] = W_aggr[i * D + j];
    sWe[i][j] = W_eu[i * D + j];
    sW1[i][j] = W_src[i * D + j];
    sW2[i][j] = W_edge[i * D + j];
    sW3[i][j] = W_rx[i * D + j];
    __syncthreads();
    float s = 0.f;
    #pragma unroll
    for (int k = 0; k < D; ++k) s += sWa[i][k] * sWe[k][j];
    sP2[i][j] = s;
    __syncthreads();
    float a = 0.f, b = 0.f, c = 0.f;
    #pragma unroll
    for (int k = 0; k < D; ++k) {
        const float p = sP2[i][k];
        a += p * sW1[k][j];
        b += p * sW2[k][j];
        c += p * sW3[k][j];
    }
    P_out[0 * D * D + i * D + j] = a;
    P_out[1 * D * D + i * D + j] = b;
    P_out[2 * D * D + i * D + j] = c;
}

// K1: bucket edges by receiver bin (v>>6). Per (block,bin) ONE cursor atomic
// reserves a contiguous run -> line-dense writes. Entry packs (e, u<<6|v&63).
// Overflow appends (e,v) to ovflist (capacity E -> can never be exceeded).
__global__ void __launch_bounds__(THREADS_A) bucket(
    const int* __restrict__ ei,
    int* __restrict__ cursor,        // [NBINS] zeroed
    uint2* __restrict__ binbuf,      // [NBINS, CAPB]
    uint2* __restrict__ ovflist,     // [E]
    int* __restrict__ ovfcnt,        // zeroed
    int E_, int NBINS, int CAPB) {
    extern __shared__ int sm[];
    int* hist = sm;              // [NBINS]
    int* cur  = sm + NBINS;      // [NBINS]
    int* sv   = sm + 2 * NBINS;  // [CHUNK_A]
    const int tid = threadIdx.x;
    for (int b = tid; b < NBINS; b += THREADS_A) hist[b] = 0;
    __syncthreads();

    const int base = blockIdx.x * CHUNK_A;
    const int m = min(CHUNK_A, E_ - base);

    for (int idx = tid; idx < m; idx += THREADS_A) {
        const int v = ei[E_ + base + idx];
        sv[idx] = v;
        atomicAdd(&hist[v >> 6], 1);
    }
    __syncthreads();

    for (int b = tid; b < NBINS; b += THREADS_A) {
        const int h = hist[b];
        cur[b] = h ? atomicAdd(&cursor[b], h) : 0;
    }
    __syncthreads();

    for (int idx = tid; idx < m; idx += THREADS_A) {
        const int u = ei[base + idx];
        const int v = sv[idx];
        const int bb = v >> 6;
        const int slot = atomicAdd(&cur[bb], 1);
        if (slot < CAPB) {
            binbuf[(size_t)bb * CAPB + slot] =
                make_uint2((unsigned)(base + idx),
                           ((unsigned)u << 6) | (unsigned)(v & 63));
        } else {
            const int pos = atomicAdd(ovfcnt, 1);  // list cap = E: always fits
            ovflist[pos] = make_uint2((unsigned)(base + idx), (unsigned)v);
        }
    }
}

// K2: counting-sort bin entries by node in LDS (2 LDS atomics/edge), then
// per-node REGISTER accumulation (no LDS atomics, no spills); plain-store
// A/B/deg (no pre-zero needed). Epilogue NOT fused (R6: 128 VGPR + spills).
__global__ void __launch_bounds__(THREADS_G) bin_gather(
    const float* __restrict__ x,
    const float* __restrict__ ea,
    const uint2* __restrict__ binbuf,
    const int* __restrict__ cursor,
    float* __restrict__ A,
    float* __restrict__ B,
    int* __restrict__ deg,
    int N_, int CAPB) {
    __shared__ uint2 ent[CAPB_MAX];
    __shared__ uint2 ordb[CAPB_MAX];
    __shared__ int cl[GN], cl2[GN], st[GN];

    const int tid = threadIdx.x;
    const int b = blockIdx.x;

    if (tid < GN) { cl[tid] = 0; cl2[tid] = 0; }
    __syncthreads();

    const int c = min(cursor[b], CAPB);
    const uint2* __restrict__ lst = binbuf + (size_t)b * CAPB;

    // load entries + per-node histogram (1 LDS atomic per entry)
    for (int i = tid; i < c; i += THREADS_G) {
        const uint2 en = lst[i];
        ent[i] = en;
        atomicAdd(&cl[en.y & 63u], 1);
    }
    __syncthreads();

    // exclusive prefix sum of cl -> st
    if (tid < GN) st[tid] = cl[tid];
    __syncthreads();
    for (int off = 1; off < GN; off <<= 1) {
        int v = 0;
        if (tid < GN && tid >= off) v = st[tid - off];
        __syncthreads();
        if (tid < GN && tid >= off) st[tid] += v;
        __syncthreads();
    }
    if (tid < GN) st[tid] -= cl[tid];
    __syncthreads();

    // counting-sort scatter (1 LDS atomic per entry)
    for (int i = tid; i < c; i += THREADS_G) {
        const uint2 en = ent[i];
        const int vl = (int)(en.y & 63u);
        const int slot = atomicAdd(&cl2[vl], 1);
        ordb[st[vl] + slot] = en;
    }
    __syncthreads();

    // per-node register gather: group g (8 lanes) owns node b*GN+g
    const int g = tid >> 3;
    const int q = tid & 7;
    const int s = st[g];
    const int len = cl[g];
    const int n = b * GN + g;

    float4 aA = {0.f, 0.f, 0.f, 0.f}, aB = {0.f, 0.f, 0.f, 0.f};
    uint2 e0 = make_uint2(0u, 0u);
    float4 xv = {0.f, 0.f, 0.f, 0.f}, ev = {0.f, 0.f, 0.f, 0.f};
    if (len > 0) {
        e0 = ordb[s];
        xv = *(const float4*)(x + (size_t)(e0.y >> 6) * D + q * 4);
        ev = *(const float4*)(ea + (size_t)e0.x * D + q * 4);
    }
    for (int i = 0; i < len; ++i) {
        uint2 e1 = e0;
        float4 xv1 = xv, ev1 = ev;
        if (i + 1 < len) {
            e1 = ordb[s + i + 1];
            xv1 = *(const float4*)(x + (size_t)(e1.y >> 6) * D + q * 4);
            ev1 = *(const float4*)(ea + (size_t)e1.x * D + q * 4);
        }
        aA.x += xv.x; aA.y += xv.y; aA.z += xv.z; aA.w += xv.w;
        aB.x += ev.x; aB.y += ev.y; aB.z += ev.z; aB.w += ev.w;
        e0 = e1; xv = xv1; ev = ev1;
    }

    if (n < N_) {
        *(float4*)(A + (size_t)n * D + q * 4) = aA;
        *(float4*)(B + (size_t)n * D + q * 4) = aB;
        if (q == 0) deg[n] = len;
    }
}

// K2b: merge overflow-list edges into A/B/deg (normally ovfcnt==0 -> no-op).
__global__ void __launch_bounds__(256) fixup(
    const float* __restrict__ x,
    const float* __restrict__ ea,
    const int* __restrict__ ei,
    const uint2* __restrict__ ovflist,
    const int* __restrict__ ovfcnt,
    float* __restrict__ A,
    float* __restrict__ B,
    int* __restrict__ deg,
    int E_) {
    const int total = *ovfcnt;
    for (int i = blockIdx.x * 256 + threadIdx.x; i < total; i += gridDim.x * 256) {
        const uint2 en = ovflist[i];
        const int e = (int)en.x;
        const int v = (int)en.y;
        const int u = ei[e];
        const float* xr = x + (size_t)u * D;
        const float* er = ea + (size_t)e * D;
        float* Ar = A + (size_t)v * D;
        float* Br = B + (size_t)v * D;
        for (int k = 0; k < D; ++k) {
            atomicAdd(Ar + k, xr[k]);
            atomicAdd(Br + k, er[k]);
        }
        atomicAdd(&deg[v], 1);
    }
}

// K3: per-node epilogue. Thread = node; weight loads are wave-uniform.
__global__ void __launch_bounds__(256) node_kernel(
    const float* __restrict__ x,
    const float* __restrict__ A,
    const float* __restrict__ B,
    const int* __restrict__ deg,
    const float* __restrict__ W_rxnode,
    const float* __restrict__ P,
    float* __restrict__ out0,
    float* __restrict__ out1,
    int N_) {
    const int n = blockIdx.x * 256 + threadIdx.x;
    if (n >= N_) return;

    float xr[D];
    #pragma unroll
    for (int kq = 0; kq < D / 4; ++kq)
        *(float4*)(xr + kq * 4) = *(const float4*)(x + (size_t)n * D + kq * 4);

    {
        float o[D];
        #pragma unroll
        for (int j = 0; j < D; ++j) {
            float s = 0.f;
            #pragma unroll
            for (int k = 0; k < D; ++k) s += xr[k] * W_rxnode[j * D + k];
            o[j] = s;
        }
        #pragma unroll
        for (int kq = 0; kq < D / 4; ++kq)
            *(float4*)(out0 + (size_t)n * D + kq * 4) = *(const float4*)(o + kq * 4);
    }

    float Ar[D], Br[D];
    #pragma unroll
    for (int kq = 0; kq < D / 4; ++kq) {
        *(float4*)(Ar + kq * 4) = *(const float4*)(A + (size_t)n * D + kq * 4);
        *(float4*)(Br + kq * 4) = *(const float4*)(B + (size_t)n * D + kq * 4);
    }
    const float dg = (float)deg[n];
    #pragma unroll
    for (int k = 0; k < D; ++k) xr[k] *= dg;  // fold deg into x row

    const float* __restrict__ Ps = P;
    const float* __restrict__ Pe = P + D * D;
    const float* __restrict__ Pr = P + 2 * D * D;
    {
        float o[D];
        #pragma unroll
        for (int j = 0; j < D; ++j) {
            float s = 0.f;
            #pragma unroll
            for (int k = 0; k < D; ++k) {
                s += Ar[k] * Ps[j * D + k];
                s += Br[k] * Pe[j * D + k];
                s += xr[k] * Pr[j * D + k];
            }
            o[j] = s;
        }
        #pragma unroll
        for (int kq = 0; kq < D / 4; ++kq)
            *(float4*)(out1 + (size_t)n * D + kq * 4) = *(const float4*)(o + kq * 4);
    }
}

extern "C" void kernel_launch(void* const* d_in, const int* in_sizes, int n_in,
                              void* d_out, int out_size, void* d_ws, size_t ws_size,
                              hipStream_t stream) {
    const float* x        = (const float*)d_in[0];
    const int*   ei       = (const int*)d_in[1];    // [2, E] int32
    const float* ea       = (const float*)d_in[2];  // [E, D]
    const float* W_src    = (const float*)d_in[3];
    const float* W_edge   = (const float*)d_in[4];
    const float* W_rx     = (const float*)d_in[5];
    const float* W_eu     = (const float*)d_in[6];
    const float* W_rxnode = (const float*)d_in[7];
    const float* W_aggr   = (const float*)d_in[8];

    const int N_ = in_sizes[0] / D;  // 100000
    const int E_ = in_sizes[2] / D;  // 2000000
    const int NBINS = (N_ + GN - 1) / GN;

    // ws layout: A[N*D] | B[N*D] | deg[N] | cursor[NBINS] | ovfcnt[1]
    //            | P[3*D*D] | pad | ovflist[E] uint2 | binbuf[NBINS*CAPB]
    float* A      = (float*)d_ws;
    float* B      = A + (size_t)N_ * D;
    int*   deg    = (int*)(B + (size_t)N_ * D);
    int*   cursor = deg + N_;
    int*   ovfcnt = cursor + NBINS;
    float* P      = (float*)(ovfcnt + 1);
    size_t off = ((size_t)2 * N_ * D + N_ + NBINS + 1 + 3 * D * D) * 4;
    off = (off + 15) & ~(size_t)15;
    uint2* ovflist = (uint2*)((char*)d_ws + off);
    uint2* binbuf  = ovflist + (size_t)E_;
    const size_t off2 = off + (size_t)E_ * 8;

    int CAPB = 0;
    if (ws_size > off2) {
        size_t c = (ws_size - off2) / ((size_t)NBINS * 8);
        CAPB = (c > CAPB_MAX) ? CAPB_MAX : (int)c;
    }

    float* out0 = (float*)d_out;
    float* out1 = out0 + (size_t)N_ * D;

    // zero only cursor + ovfcnt (~6 KB) with a tiny kernel
    zero_small<<<(NBINS + 1 + 255) / 256, 256, 0, stream>>>(cursor, NBINS + 1);

    combine_weights<<<1, dim3(32, 32), 0, stream>>>(W_src, W_edge, W_rx, W_eu, W_aggr, P);

    const int gridA = (E_ + CHUNK_A - 1) / CHUNK_A;
    const size_t smA = (size_t)(2 * NBINS + CHUNK_A) * sizeof(int);
    bucket<<<gridA, THREADS_A, smA, stream>>>(
        ei, cursor, binbuf, ovflist, ovfcnt, E_, NBINS, CAPB);

    bin_gather<<<NBINS, THREADS_G, 0, stream>>>(
        x, ea, binbuf, cursor, A, B, deg, N_, CAPB);

    fixup<<<64, 256, 0, stream>>>(x, ea, ei, ovflist, ovfcnt, A, B, deg, E_);

    node_kernel<<<(N_ + 255) / 256, 256, 0, stream>>>(
        x, A, B, deg, W_rxnode, P, out0, out1, N_);
}

// Round 10
// 230.133 us; speedup vs baseline: 1.1589x; 1.1589x over previous
//
#include <hip/hip_runtime.h>

#define D 32
#define GN 64            // receiver nodes per bin
#define CAPB_MAX 1600    // entries per bin (avg 1280, +8.9 sigma)
#define CHUNK_A 4096     // edges per bucket block (489 blocks -> ~2/CU)
#define THREADS_A 512
#define THREADS_G 512

typedef float vf4 __attribute__((ext_vector_type(4)));  // nontemporal-compatible

// K-1: zero cursor + ovfcnt (~6 KB).
__global__ void zero_small(int* __restrict__ p, int n) {
    const int i = blockIdx.x * 256 + threadIdx.x;
    if (i < n) p[i] = 0;
}

// K0: P_src = W_aggr @ W_eu @ W_src, similarly edge, rx. One block (32,32).
__global__ void combine_weights(const float* __restrict__ W_src,
                                const float* __restrict__ W_edge,
                                const float* __restrict__ W_rx,
                                const float* __restrict__ W_eu,
                                const float* __restrict__ W_aggr,
                                float* __restrict__ P_out) {
    __shared__ float sWa[D][D], sWe[D][D], sP2[D][D + 1];
    __shared__ float sW1[D][D], sW2[D][D], sW3[D][D];
    const int j = threadIdx.x, i = threadIdx.y;
    sWa[i][j] = W_aggr[i * D + j];
    sWe[i][j] = W_eu[i * D + j];
    sW1[i][j] = W_src[i * D + j];
    sW2[i][j] = W_edge[i * D + j];
    sW3[i][j] = W_rx[i * D + j];
    __syncthreads();
    float s = 0.f;
    #pragma unroll
    for (int k = 0; k < D; ++k) s += sWa[i][k] * sWe[k][j];
    sP2[i][j] = s;
    __syncthreads();
    float a = 0.f, b = 0.f, c = 0.f;
    #pragma unroll
    for (int k = 0; k < D; ++k) {
        const float p = sP2[i][k];
        a += p * sW1[k][j];
        b += p * sW2[k][j];
        c += p * sW3[k][j];
    }
    P_out[0 * D * D + i * D + j] = a;
    P_out[1 * D * D + i * D + j] = b;
    P_out[2 * D * D + i * D + j] = c;
}

// K1: bucket edges by receiver bin (v>>6). Per (block,bin) ONE cursor atomic
// reserves a contiguous run -> line-dense writes. Entry packs (e, u<<6|v&63).
// Overflow appends (e,v) to ovflist (capacity E -> can never be exceeded).
__global__ void __launch_bounds__(THREADS_A) bucket(
    const int* __restrict__ ei,
    int* __restrict__ cursor,        // [NBINS] zeroed
    uint2* __restrict__ binbuf,      // [NBINS, CAPB]
    uint2* __restrict__ ovflist,     // [E]
    int* __restrict__ ovfcnt,        // zeroed
    int E_, int NBINS, int CAPB) {
    extern __shared__ int sm[];
    int* hist = sm;              // [NBINS]
    int* cur  = sm + NBINS;      // [NBINS]
    int* sv   = sm + 2 * NBINS;  // [CHUNK_A]
    const int tid = threadIdx.x;
    for (int b = tid; b < NBINS; b += THREADS_A) hist[b] = 0;
    __syncthreads();

    const int base = blockIdx.x * CHUNK_A;
    const int m = min(CHUNK_A, E_ - base);

    for (int idx = tid; idx < m; idx += THREADS_A) {
        const int v = ei[E_ + base + idx];
        sv[idx] = v;
        atomicAdd(&hist[v >> 6], 1);
    }
    __syncthreads();

    for (int b = tid; b < NBINS; b += THREADS_A) {
        const int h = hist[b];
        cur[b] = h ? atomicAdd(&cursor[b], h) : 0;
    }
    __syncthreads();

    for (int idx = tid; idx < m; idx += THREADS_A) {
        const int u = ei[base + idx];
        const int v = sv[idx];
        const int bb = v >> 6;
        const int slot = atomicAdd(&cur[bb], 1);
        if (slot < CAPB) {
            binbuf[(size_t)bb * CAPB + slot] =
                make_uint2((unsigned)(base + idx),
                           ((unsigned)u << 6) | (unsigned)(v & 63));
        } else {
            const int pos = atomicAdd(ovfcnt, 1);  // list cap = E: always fits
            ovflist[pos] = make_uint2((unsigned)(base + idx), (unsigned)v);
        }
    }
}

// K2: counting-sort bin entries by node in LDS, then per-node REGISTER
// accumulation with a DEPTH-3 software-pipeline ring (static slots — runtime
// ring indices would spill to scratch). ea rows loaded nontemporal (read-once;
// keep L2 for x/binbuf). Plain stores of A/B/deg.
__global__ void __launch_bounds__(THREADS_G) bin_gather(
    const float* __restrict__ x,
    const float* __restrict__ ea,
    const uint2* __restrict__ binbuf,
    const int* __restrict__ cursor,
    float* __restrict__ A,
    float* __restrict__ B,
    int* __restrict__ deg,
    int N_, int CAPB) {
    __shared__ uint2 ent[CAPB_MAX];
    __shared__ uint2 ordb[CAPB_MAX];
    __shared__ int cl[GN], cl2[GN], st[GN];

    const int tid = threadIdx.x;
    const int b = blockIdx.x;

    if (tid < GN) { cl[tid] = 0; cl2[tid] = 0; }
    __syncthreads();

    const int c = min(cursor[b], CAPB);
    const uint2* __restrict__ lst = binbuf + (size_t)b * CAPB;

    for (int i = tid; i < c; i += THREADS_G) {
        const uint2 en = lst[i];
        ent[i] = en;
        atomicAdd(&cl[en.y & 63u], 1);
    }
    __syncthreads();

    if (tid < GN) st[tid] = cl[tid];
    __syncthreads();
    for (int off = 1; off < GN; off <<= 1) {
        int v = 0;
        if (tid < GN && tid >= off) v = st[tid - off];
        __syncthreads();
        if (tid < GN && tid >= off) st[tid] += v;
        __syncthreads();
    }
    if (tid < GN) st[tid] -= cl[tid];
    __syncthreads();

    for (int i = tid; i < c; i += THREADS_G) {
        const uint2 en = ent[i];
        const int vl = (int)(en.y & 63u);
        const int slot = atomicAdd(&cl2[vl], 1);
        ordb[st[vl] + slot] = en;
    }
    __syncthreads();

    // per-node register gather: group g (8 lanes) owns node b*GN+g.
    // sorted => every entry in [s, s+len) has vl == g.
    const int g = tid >> 3;
    const int q = tid & 7;
    const int s = st[g];
    const int len = cl[g];
    const int n = b * GN + g;

    vf4 aA = {0.f, 0.f, 0.f, 0.f}, aB = {0.f, 0.f, 0.f, 0.f};

    uint2 E0, E1, E2;
    vf4 X0 = {0,0,0,0}, X1 = {0,0,0,0}, X2 = {0,0,0,0};
    vf4 V0 = {0,0,0,0}, V1 = {0,0,0,0}, V2 = {0,0,0,0};

    #define LDX(EN) (*(const vf4*)(x + (size_t)((EN).y >> 6) * D + q * 4))
    #define LDV(EN) (__builtin_nontemporal_load((const vf4*)(ea + (size_t)(EN).x * D + q * 4)))

    if (len > 0) { E0 = ordb[s];     X0 = LDX(E0); V0 = LDV(E0); }
    if (len > 1) { E1 = ordb[s + 1]; X1 = LDX(E1); V1 = LDV(E1); }
    if (len > 2) { E2 = ordb[s + 2]; X2 = LDX(E2); V2 = LDV(E2); }

    int i = 0;
    for (; i + 3 <= len; i += 3) {
        aA += X0; aB += V0;
        if (i + 3 < len) { E0 = ordb[s + i + 3]; X0 = LDX(E0); V0 = LDV(E0); }

        aA += X1; aB += V1;
        if (i + 4 < len) { E1 = ordb[s + i + 4]; X1 = LDX(E1); V1 = LDV(E1); }

        aA += X2; aB += V2;
        if (i + 5 < len) { E2 = ordb[s + i + 5]; X2 = LDX(E2); V2 = LDV(E2); }
    }
    // tail: r = len - i in {0,1,2}
    if (i < len)     { aA += X0; aB += V0; }
    if (i + 1 < len) { aA += X1; aB += V1; }
    #undef LDX
    #undef LDV

    if (n < N_) {
        *(vf4*)(A + (size_t)n * D + q * 4) = aA;
        *(vf4*)(B + (size_t)n * D + q * 4) = aB;
        if (q == 0) deg[n] = len;
    }
}

// K2b: merge overflow-list edges into A/B/deg (normally ovfcnt==0 -> no-op).
__global__ void __launch_bounds__(256) fixup(
    const float* __restrict__ x,
    const float* __restrict__ ea,
    const int* __restrict__ ei,
    const uint2* __restrict__ ovflist,
    const int* __restrict__ ovfcnt,
    float* __restrict__ A,
    float* __restrict__ B,
    int* __restrict__ deg,
    int E_) {
    const int total = *ovfcnt;
    for (int i = blockIdx.x * 256 + threadIdx.x; i < total; i += gridDim.x * 256) {
        const uint2 en = ovflist[i];
        const int e = (int)en.x;
        const int v = (int)en.y;
        const int u = ei[e];
        const float* xr = x + (size_t)u * D;
        const float* er = ea + (size_t)e * D;
        float* Ar = A + (size_t)v * D;
        float* Br = B + (size_t)v * D;
        for (int k = 0; k < D; ++k) {
            atomicAdd(Ar + k, xr[k]);
            atomicAdd(Br + k, er[k]);
        }
        atomicAdd(&deg[v], 1);
    }
}

// K3: per-node epilogue. Thread = node; weight loads are wave-uniform.
__global__ void __launch_bounds__(256) node_kernel(
    const float* __restrict__ x,
    const float* __restrict__ A,
    const float* __restrict__ B,
    const int* __restrict__ deg,
    const float* __restrict__ W_rxnode,
    const float* __restrict__ P,
    float* __restrict__ out0,
    float* __restrict__ out1,
    int N_) {
    const int n = blockIdx.x * 256 + threadIdx.x;
    if (n >= N_) return;

    float xr[D];
    #pragma unroll
    for (int kq = 0; kq < D / 4; ++kq)
        *(float4*)(xr + kq * 4) = *(const float4*)(x + (size_t)n * D + kq * 4);

    {
        float o[D];
        #pragma unroll
        for (int j = 0; j < D; ++j) {
            float s = 0.f;
            #pragma unroll
            for (int k = 0; k < D; ++k) s += xr[k] * W_rxnode[j * D + k];
            o[j] = s;
        }
        #pragma unroll
        for (int kq = 0; kq < D / 4; ++kq)
            *(float4*)(out0 + (size_t)n * D + kq * 4) = *(const float4*)(o + kq * 4);
    }

    float Ar[D], Br[D];
    #pragma unroll
    for (int kq = 0; kq < D / 4; ++kq) {
        *(float4*)(Ar + kq * 4) = *(const float4*)(A + (size_t)n * D + kq * 4);
        *(float4*)(Br + kq * 4) = *(const float4*)(B + (size_t)n * D + kq * 4);
    }
    const float dg = (float)deg[n];
    #pragma unroll
    for (int k = 0; k < D; ++k) xr[k] *= dg;  // fold deg into x row

    const float* __restrict__ Ps = P;
    const float* __restrict__ Pe = P + D * D;
    const float* __restrict__ Pr = P + 2 * D * D;
    {
        float o[D];
        #pragma unroll
        for (int j = 0; j < D; ++j) {
            float s = 0.f;
            #pragma unroll
            for (int k = 0; k < D; ++k) {
                s += Ar[k] * Ps[j * D + k];
                s += Br[k] * Pe[j * D + k];
                s += xr[k] * Pr[j * D + k];
            }
            o[j] = s;
        }
        #pragma unroll
        for (int kq = 0; kq < D / 4; ++kq)
            *(float4*)(out1 + (size_t)n * D + kq * 4) = *(const float4*)(o + kq * 4);
    }
}

extern "C" void kernel_launch(void* const* d_in, const int* in_sizes, int n_in,
                              void* d_out, int out_size, void* d_ws, size_t ws_size,
                              hipStream_t stream) {
    const float* x        = (const float*)d_in[0];
    const int*   ei       = (const int*)d_in[1];    // [2, E] int32
    const float* ea       = (const float*)d_in[2];  // [E, D]
    const float* W_src    = (const float*)d_in[3];
    const float* W_edge   = (const float*)d_in[4];
    const float* W_rx     = (const float*)d_in[5];
    const float* W_eu     = (const float*)d_in[6];
    const float* W_rxnode = (const float*)d_in[7];
    const float* W_aggr   = (const float*)d_in[8];

    const int N_ = in_sizes[0] / D;  // 100000
    const int E_ = in_sizes[2] / D;  // 2000000
    const int NBINS = (N_ + GN - 1) / GN;

    // ws layout: A[N*D] | B[N*D] | deg[N] | cursor[NBINS] | ovfcnt[1]
    //            | P[3*D*D] | pad | ovflist[E] uint2 | binbuf[NBINS*CAPB]
    float* A      = (float*)d_ws;
    float* B      = A + (size_t)N_ * D;
    int*   deg    = (int*)(B + (size_t)N_ * D);
    int*   cursor = deg + N_;
    int*   ovfcnt = cursor + NBINS;
    float* P      = (float*)(ovfcnt + 1);
    size_t off = ((size_t)2 * N_ * D + N_ + NBINS + 1 + 3 * D * D) * 4;
    off = (off + 15) & ~(size_t)15;
    uint2* ovflist = (uint2*)((char*)d_ws + off);
    uint2* binbuf  = ovflist + (size_t)E_;
    const size_t off2 = off + (size_t)E_ * 8;

    int CAPB = 0;
    if (ws_size > off2) {
        size_t c = (ws_size - off2) / ((size_t)NBINS * 8);
        CAPB = (c > CAPB_MAX) ? CAPB_MAX : (int)c;
    }

    float* out0 = (float*)d_out;
    float* out1 = out0 + (size_t)N_ * D;

    zero_small<<<(NBINS + 1 + 255) / 256, 256, 0, stream>>>(cursor, NBINS + 1);

    combine_weights<<<1, dim3(32, 32), 0, stream>>>(W_src, W_edge, W_rx, W_eu, W_aggr, P);

    const int gridA = (E_ + CHUNK_A - 1) / CHUNK_A;
    const size_t smA = (size_t)(2 * NBINS + CHUNK_A) * sizeof(int);
    bucket<<<gridA, THREADS_A, smA, stream>>>(
        ei, cursor, binbuf, ovflist, ovfcnt, E_, NBINS, CAPB);

    bin_gather<<<NBINS, THREADS_G, 0, stream>>>(
        x, ea, binbuf, cursor, A, B, deg, N_, CAPB);

    fixup<<<64, 256, 0, stream>>>(x, ea, ei, ovflist, ovfcnt, A, B, deg, E_);

    node_kernel<<<(N_ + 255) / 256, 256, 0, stream>>>(
        x, A, B, deg, W_rxnode, P, out0, out1, N_);
}

// Round 11
// 213.319 us; speedup vs baseline: 1.2502x; 1.0788x over previous
//
#include <hip/hip_runtime.h>

#define D 32
#define GN 64            // receiver nodes per bin
#define CAPB_MAX 1600    // entries per bin (avg 1280, +8.9 sigma)
#define CHUNK_A 4096     // edges per bucket block
#define THREADS_A 512
#define THREADS_G 512
#define WPAD 36          // weight LDS row pad: 9k+q 16B-units -> conflict-free b128

typedef float vf4 __attribute__((ext_vector_type(4)));

// K0: P_src = W_aggr @ W_eu @ W_src (etc) + zero cursor/ovfcnt (folded in).
__global__ void combine_weights(const float* __restrict__ W_src,
                                const float* __restrict__ W_edge,
                                const float* __restrict__ W_rx,
                                const float* __restrict__ W_eu,
                                const float* __restrict__ W_aggr,
                                float* __restrict__ P_out,
                                int* __restrict__ zero_p, int nzero) {
    __shared__ float sWa[D][D], sWe[D][D], sP2[D][D + 1];
    __shared__ float sW1[D][D], sW2[D][D], sW3[D][D];
    const int j = threadIdx.x, i = threadIdx.y;
    const int tid = i * D + j;
    for (int z = tid; z < nzero; z += D * D) zero_p[z] = 0;
    sWa[i][j] = W_aggr[i * D + j];
    sWe[i][j] = W_eu[i * D + j];
    sW1[i][j] = W_src[i * D + j];
    sW2[i][j] = W_edge[i * D + j];
    sW3[i][j] = W_rx[i * D + j];
    __syncthreads();
    float s = 0.f;
    #pragma unroll
    for (int k = 0; k < D; ++k) s += sWa[i][k] * sWe[k][j];
    sP2[i][j] = s;
    __syncthreads();
    float a = 0.f, b = 0.f, c = 0.f;
    #pragma unroll
    for (int k = 0; k < D; ++k) {
        const float p = sP2[i][k];
        a += p * sW1[k][j];
        b += p * sW2[k][j];
        c += p * sW3[k][j];
    }
    P_out[0 * D * D + i * D + j] = a;
    P_out[1 * D * D + i * D + j] = b;
    P_out[2 * D * D + i * D + j] = c;
}

// K1: bucket edges by receiver bin (v>>6). Per (block,bin) ONE cursor atomic
// reserves a contiguous run. sv cache dropped (ei v-half is L2-hot on reread)
// -> LDS 12.5 KB. Overflow appends to ovflist (cap E: can never be exceeded).
__global__ void __launch_bounds__(THREADS_A) bucket(
    const int* __restrict__ ei,
    int* __restrict__ cursor,        // [NBINS] zeroed
    uint2* __restrict__ binbuf,      // [NBINS, CAPB]
    uint2* __restrict__ ovflist,     // [E]
    int* __restrict__ ovfcnt,        // zeroed
    int E_, int NBINS, int CAPB) {
    extern __shared__ int sm[];
    int* hist = sm;          // [NBINS]
    int* cur  = sm + NBINS;  // [NBINS]
    const int tid = threadIdx.x;
    for (int b = tid; b < NBINS; b += THREADS_A) hist[b] = 0;
    __syncthreads();

    const int base = blockIdx.x * CHUNK_A;
    const int m = min(CHUNK_A, E_ - base);

    for (int idx = tid; idx < m; idx += THREADS_A)
        atomicAdd(&hist[ei[E_ + base + idx] >> 6], 1);
    __syncthreads();

    for (int b = tid; b < NBINS; b += THREADS_A) {
        const int h = hist[b];
        cur[b] = h ? atomicAdd(&cursor[b], h) : 0;
    }
    __syncthreads();

    for (int idx = tid; idx < m; idx += THREADS_A) {
        const int u = ei[base + idx];
        const int v = ei[E_ + base + idx];   // L2-hot reread
        const int bb = v >> 6;
        const int slot = atomicAdd(&cur[bb], 1);
        if (slot < CAPB) {
            binbuf[(size_t)bb * CAPB + slot] =
                make_uint2((unsigned)(base + idx),
                           ((unsigned)u << 6) | (unsigned)(v & 63));
        } else {
            const int pos = atomicAdd(ovfcnt, 1);  // cap E: always fits
            ovflist[pos] = make_uint2((unsigned)(base + idx), (unsigned)v);
        }
    }
}

// K2 (fused): counting-sort by node in LDS -> depth-3 pipelined register
// gather -> in-kernel overflow merge -> epilogue via width-8 shfl + LDS
// transposed weights. No A/B/deg buffers, no node_kernel, no fixup.
__global__ void __launch_bounds__(THREADS_G) bin_gather(
    const float* __restrict__ x,
    const float* __restrict__ ea,
    const int* __restrict__ ei,
    const uint2* __restrict__ binbuf,
    const int* __restrict__ cursor,
    const uint2* __restrict__ ovflist,
    const int* __restrict__ ovfcnt,
    const float* __restrict__ W_rxnode,
    const float* __restrict__ P,     // Ps, Pe, Pr
    float* __restrict__ out0,
    float* __restrict__ out1,
    int N_, int CAPB) {
    __shared__ uint2 ordb[CAPB_MAX];
    __shared__ int cl[GN], cl2[GN], st[GN];
    // weights TRANSPOSED: w[k][j] = W[j][k]; pad WPAD=36 -> b128 addr
    // (9k+q) 16B-units: q consecutive across lanes = conflict-free.
    __shared__ float wrx[D][WPAD], wps[D][WPAD], wpe[D][WPAD], wpr[D][WPAD];

    const int tid = threadIdx.x;
    const int b = blockIdx.x;

    for (int idx = tid; idx < D * D; idx += THREADS_G) {
        const int k = idx >> 5, j = idx & 31;
        wrx[k][j] = W_rxnode[j * D + k];
        wps[k][j] = P[j * D + k];
        wpe[k][j] = P[D * D + j * D + k];
        wpr[k][j] = P[2 * D * D + j * D + k];
    }
    if (tid < GN) { cl[tid] = 0; cl2[tid] = 0; }
    __syncthreads();

    const int c = min(cursor[b], CAPB);
    const uint2* __restrict__ lst = binbuf + (size_t)b * CAPB;

    // histogram (lst read 1; L2-hot — ent LDS copy dropped for weight space)
    for (int i = tid; i < c; i += THREADS_G)
        atomicAdd(&cl[lst[i].y & 63u], 1);
    __syncthreads();

    // exclusive prefix sum cl -> st
    if (tid < GN) st[tid] = cl[tid];
    __syncthreads();
    for (int off = 1; off < GN; off <<= 1) {
        int v = 0;
        if (tid < GN && tid >= off) v = st[tid - off];
        __syncthreads();
        if (tid < GN && tid >= off) st[tid] += v;
        __syncthreads();
    }
    if (tid < GN) st[tid] -= cl[tid];
    __syncthreads();

    // counting-sort scatter (lst read 2)
    for (int i = tid; i < c; i += THREADS_G) {
        const uint2 en = lst[i];
        const int vl = (int)(en.y & 63u);
        const int slot = atomicAdd(&cl2[vl], 1);
        ordb[st[vl] + slot] = en;
    }
    __syncthreads();

    // depth-3 pipelined register gather: group g (8 lanes) owns node b*GN+g
    const int g = tid >> 3;
    const int q = tid & 7;
    const int s = st[g];
    const int len = cl[g];
    const int n = b * GN + g;

    vf4 aA = {0.f, 0.f, 0.f, 0.f}, aB = {0.f, 0.f, 0.f, 0.f};
    uint2 E0 = make_uint2(0u, 0u), E1 = E0, E2 = E0;
    vf4 X0 = {0,0,0,0}, X1 = {0,0,0,0}, X2 = {0,0,0,0};
    vf4 V0 = {0,0,0,0}, V1 = {0,0,0,0}, V2 = {0,0,0,0};

    #define LDX(EN) (*(const vf4*)(x + (size_t)((EN).y >> 6) * D + q * 4))
    #define LDV(EN) (__builtin_nontemporal_load((const vf4*)(ea + (size_t)(EN).x * D + q * 4)))

    if (len > 0) { E0 = ordb[s];     X0 = LDX(E0); V0 = LDV(E0); }
    if (len > 1) { E1 = ordb[s + 1]; X1 = LDX(E1); V1 = LDV(E1); }
    if (len > 2) { E2 = ordb[s + 2]; X2 = LDX(E2); V2 = LDV(E2); }

    int i = 0;
    for (; i + 3 <= len; i += 3) {
        aA += X0; aB += V0;
        if (i + 3 < len) { E0 = ordb[s + i + 3]; X0 = LDX(E0); V0 = LDV(E0); }
        aA += X1; aB += V1;
        if (i + 4 < len) { E1 = ordb[s + i + 4]; X1 = LDX(E1); V1 = LDV(E1); }
        aA += X2; aB += V2;
        if (i + 5 < len) { E2 = ordb[s + i + 5]; X2 = LDX(E2); V2 = LDV(E2); }
    }
    if (i < len)     { aA += X0; aB += V0; }
    if (i + 1 < len) { aA += X1; aB += V1; }
    #undef LDX
    #undef LDV

    // overflow merge (normally *ovfcnt == 0)
    int dtot = len;
    const int otot = *ovfcnt;
    if (otot > 0) {
        for (int oi = 0; oi < otot; ++oi) {
            const uint2 en = ovflist[oi];
            const int v = (int)en.y;
            if ((v >> 6) == b && (v & 63) == g) {
                const int e = (int)en.x;
                const int u = ei[e];
                aA += *(const vf4*)(x + (size_t)u * D + q * 4);
                aB += *(const vf4*)(ea + (size_t)e * D + q * 4);
                ++dtot;
            }
        }
    }

    // fused epilogue: lane q of group g computes out[j], j = 4q..4q+3.
    // Cross-k via width-8 shfl; dtot is group-uniform (no shfl needed).
    vf4 xn4 = {0.f, 0.f, 0.f, 0.f};
    if (n < N_) xn4 = *(const vf4*)(x + (size_t)n * D + q * 4);
    const float dgf = (float)dtot;
    vf4 o0 = {0.f, 0.f, 0.f, 0.f}, o1 = {0.f, 0.f, 0.f, 0.f};
    #pragma unroll
    for (int src = 0; src < 8; ++src) {
        vf4 a4, b4, x4;
        #pragma unroll
        for (int t = 0; t < 4; ++t) {
            a4[t] = __shfl(aA[t], src, 8);
            b4[t] = __shfl(aB[t], src, 8);
            x4[t] = __shfl(xn4[t], src, 8);
        }
        const int kb = src * 4;
        #pragma unroll
        for (int t = 0; t < 4; ++t) {
            const int k = kb + t;
            const vf4 w0 = *(const vf4*)&wrx[k][q * 4];
            const vf4 w1 = *(const vf4*)&wps[k][q * 4];
            const vf4 w2 = *(const vf4*)&wpe[k][q * 4];
            const vf4 w3 = *(const vf4*)&wpr[k][q * 4];
            const float xd = x4[t] * dgf;
            o0 += x4[t] * w0;
            o1 += a4[t] * w1 + b4[t] * w2 + xd * w3;
        }
    }
    if (n < N_) {
        *(vf4*)(out0 + (size_t)n * D + q * 4) = o0;
        *(vf4*)(out1 + (size_t)n * D + q * 4) = o1;
    }
}

extern "C" void kernel_launch(void* const* d_in, const int* in_sizes, int n_in,
                              void* d_out, int out_size, void* d_ws, size_t ws_size,
                              hipStream_t stream) {
    const float* x        = (const float*)d_in[0];
    const int*   ei       = (const int*)d_in[1];    // [2, E] int32
    const float* ea       = (const float*)d_in[2];  // [E, D]
    const float* W_src    = (const float*)d_in[3];
    const float* W_edge   = (const float*)d_in[4];
    const float* W_rx     = (const float*)d_in[5];
    const float* W_eu     = (const float*)d_in[6];
    const float* W_rxnode = (const float*)d_in[7];
    const float* W_aggr   = (const float*)d_in[8];

    const int N_ = in_sizes[0] / D;  // 100000
    const int E_ = in_sizes[2] / D;  // 2000000
    const int NBINS = (N_ + GN - 1) / GN;

    // ws layout: cursor[NBINS] | ovfcnt[1] | P[3*D*D] | pad
    //            | ovflist[E] uint2 | binbuf[NBINS*CAPB] uint2
    int*   cursor = (int*)d_ws;
    int*   ovfcnt = cursor + NBINS;
    float* P      = (float*)(ovfcnt + 1);
    size_t off = ((size_t)NBINS + 1 + 3 * D * D) * 4;
    off = (off + 15) & ~(size_t)15;
    uint2* ovflist = (uint2*)((char*)d_ws + off);
    uint2* binbuf  = ovflist + (size_t)E_;
    const size_t off2 = off + (size_t)E_ * 8;

    int CAPB = 0;
    if (ws_size > off2) {
        size_t c = (ws_size - off2) / ((size_t)NBINS * 8);
        CAPB = (c > CAPB_MAX) ? CAPB_MAX : (int)c;
    }

    float* out0 = (float*)d_out;
    float* out1 = out0 + (size_t)N_ * D;

    // combine weights + zero cursor/ovfcnt in one 1-block launch
    combine_weights<<<1, dim3(32, 32), 0, stream>>>(
        W_src, W_edge, W_rx, W_eu, W_aggr, P, cursor, NBINS + 1);

    const int gridA = (E_ + CHUNK_A - 1) / CHUNK_A;
    const size_t smA = (size_t)(2 * NBINS) * sizeof(int);
    bucket<<<gridA, THREADS_A, smA, stream>>>(
        ei, cursor, binbuf, ovflist, ovfcnt, E_, NBINS, CAPB);

    bin_gather<<<NBINS, THREADS_G, 0, stream>>>(
        x, ea, ei, binbuf, cursor, ovflist, ovfcnt,
        W_rxnode, P, out0, out1, N_, CAPB);
}